// Round 10
// baseline (3464.680 us; speedup 1.0000x reference)
//
#include <hip/hip_runtime.h>
#include <hip/hip_bf16.h>

// Problem constants
#define BSN   2500   // nodes
#define TT    400    // time steps
#define DIN   16     // input dim
#define HS    32     // hidden dim
#define G4    128    // 4*HS
#define NBLK  157    // blocks (16 rows each)
#define NTHR  512    // 8 waves: 2 waves/SIMD for latency overlap
#define ROWS  16     // nodes per block (MFMA M-tile)
#define MPAD  (NBLK * ROWS)   // 2512 padded rows
#define KPAD  2528            // 79*32 (proven adj layout)
#define NCHUNK 79
#define HPAD  36              // fp32 LDS row pad
#define FLAGSTRIDE 16         // uints between flags (64 B)

// Fragment-ordered q slice (ring mode):
//   region r (r=0: h rows 0-15, r=1: h rows 16-31), chunk c (32 nodes),
//   byte addr = r*REGBYTES + c*1024 + lane*16 holds the 16 B MFMA-B fragment
//   for lane `lane` of chunk c. Producer block b (c=b>>1, half=b&1) owns the
//   contiguous 512 B [c*1024+half*512, +512) of each region.
#define REGUS   (NCHUNK * 512)          // region size in ushorts (40448)

// workspace layout (bytes) — identical to prior rounds
#define WS_FLAGS_OFF  0
#define WS_ADJ_OFF    16384
#define WS_ADJ_BYTES  ((size_t)MPAD * KPAD * 2)
#define WS_QT_OFF     (WS_ADJ_OFF + WS_ADJ_BYTES)
#define QT_SLICE      ((size_t)HS * KPAD)
#define WS_NEED_RING  (WS_QT_OFF + (size_t)TT * QT_SLICE * 2)   // ~77.4 MB

typedef __attribute__((ext_vector_type(8))) __bf16 bf16x8;
typedef __attribute__((ext_vector_type(4))) float floatx4;
typedef unsigned short ushort_t;
typedef unsigned long long u64_t;

__device__ __forceinline__ float sigmoid_fast(float v) {
    return 1.0f / (1.0f + __expf(-v));
}
__device__ __forceinline__ float tanh_fast(float v) {
    float e = __expf(2.0f * v);
    return 1.0f - 2.0f / (e + 1.0f);
}
__device__ __forceinline__ ushort_t f2bf(float f) {
    union { float f; unsigned u; } x; x.f = f;
    unsigned r = x.u + 0x7fffu + ((x.u >> 16) & 1u);  // RNE
    return (ushort_t)(r >> 16);
}

// Per-launch prep (d_ws re-poisoned 0xAA before every timed launch).
// Also pre-writes out = 12345.0 (sentinel): if the cooperative launch below is
// rejected at submit time, absmax ~1.23e4 flags it (vs 3.9e-3 "correct").
__global__ void prep(const float* __restrict__ adj, ushort_t* __restrict__ adj_bf,
                     ushort_t* __restrict__ qT, unsigned* __restrict__ flags,
                     float* __restrict__ out, int out_n) {
    const size_t idx0 = (size_t)blockIdx.x * blockDim.x + threadIdx.x;
    const size_t stride = (size_t)gridDim.x * blockDim.x;
    const size_t total = (size_t)MPAD * KPAD;
    for (size_t idx = idx0; idx < total; idx += stride) {
        int r = (int)(idx / KPAD);
        int k = (int)(idx - (size_t)r * KPAD);
        float v = (r < BSN && k < BSN) ? adj[(size_t)r * BSN + k] : 0.0f;
        adj_bf[idx] = f2bf(v);
    }
    for (size_t idx = idx0; idx < 2 * QT_SLICE; idx += stride) qT[idx] = 0;
    for (size_t idx = idx0; idx < (size_t)out_n; idx += stride) out[idx] = 12345.0f;
    if (idx0 < NBLK * FLAGSTRIDE) flags[idx0] = 0;
}

#define QLOAD(p) __hip_atomic_load((p), __ATOMIC_RELAXED, __HIP_MEMORY_SCOPE_AGENT)

// R10 P2: batch-issue all q fragment loads (R6/R8-proven pattern), run the
// `mid` section (x(t+1) prefetch issue + gates VALU work) INSIDE the load
// latency window, then MFMA. sched_barrier(0) fences pin the phase order;
// the x prefetch is issued AFTER the q loads so MFMA's counted-vmcnt wait
// does not include the HBM x load. Bit-identical numerics vs R8.
template<int NC, class F>
__device__ __forceinline__ void p2_gates(const ushort_t* __restrict__ afrag,
                                         const ushort_t* __restrict__ q0,
                                         const ushort_t* __restrict__ q1,
                                         const int cbeg, F&& mid,
                                         floatx4& acc0, floatx4& acc1) {
    bf16x8 b0[NC], b1[NC];
#pragma unroll
    for (int i = 0; i < NC; i++) {
        b0[i] = *(const bf16x8*)(q0 + (size_t)(cbeg + i) * 512);
        b1[i] = *(const bf16x8*)(q1 + (size_t)(cbeg + i) * 512);
    }
    __builtin_amdgcn_sched_barrier(0);   // q loads stay above
    mid();                               // x prefetch + gates, under load RTT
    __builtin_amdgcn_sched_barrier(0);   // MFMAs stay below
#pragma unroll
    for (int i = 0; i < NC; i++) {
        bf16x8 av = *(const bf16x8*)(afrag + (size_t)(cbeg + i) * 512);
        acc0 = __builtin_amdgcn_mfma_f32_16x16x32_bf16(av, b0[i], acc0, 0, 0, 0);
        acc1 = __builtin_amdgcn_mfma_f32_16x16x32_bf16(av, b1[i], acc1, 0, 0, 0);
    }
}

// Persistent cooperative kernel, 512 threads (8 waves), block b owns nodes
// [16b,16b+16).
// R10 = R8 (proven 1640 us steady; drain KEPT — R4/R9 proved it load-bearing)
// with ONE scheduling change in the ring path, waves 1-7:
//   R8:  x_lds -> gates -> poll -> q loads -> (RTT) -> MFMA
//   R10: x_lds -> poll -> q loads -> [x prefetch + gates under RTT] -> MFMA
// Gates leave the serial chain (hidden under the q-load round trip) and the
// poll starts ~0.5 us earlier. All other code identical to R8.
template<bool RING>
__global__ void __launch_bounds__(NTHR, 2) rgcn_main(
    const float* __restrict__ x,      // [BSN][TT][DIN]
    const float* __restrict__ W_ih,   // [DIN][G4]
    const float* __restrict__ W_hh,   // [HS][G4]
    const float* __restrict__ bias,   // [G4]
    const float* __restrict__ W_q,    // [HS][HS]
    const float* __restrict__ b_q,    // [HS]
    const float* __restrict__ W_d,    // [HS]
    const float* __restrict__ b_d,    // [1]
    const ushort_t* __restrict__ adj_bf, // [MPAD][KPAD] bf16
    ushort_t* __restrict__ qT,        // ring: [TT] fragment slices; parity: [2][HS][KPAD]
    unsigned* __restrict__ flags,     // [NBLK] generation flags, FLAGSTRIDE apart
    float* __restrict__ out)          // [BSN][TT]
{
    const int tid  = threadIdx.x;
    const int blk  = blockIdx.x;
    const int base = blk * ROWS;
    const int wv   = tid >> 6;        // wave 0..7
    const int lane = tid & 63;

    __shared__ __align__(16) ushort_t adj_lds[NCHUNK * 512];  // 79 KB, fragment order
    __shared__ __align__(16) ushort_t q_pack[512];            // 1 KB publish staging (ring)
    __shared__ __align__(16) float x_lds[ROWS][DIN];
    __shared__ __align__(16) float h_lds[ROWS][HPAD];
    __shared__ __align__(16) float c_lds[ROWS][HPAD];         // parity path only
    __shared__ __align__(16) float q_lds[ROWS][HPAD];         // parity path only
    __shared__ __align__(16) float out_lds[ROWS][16];         // 16-step out buffer
    __shared__ float gates_lds[ROWS][G4];
    __shared__ float part[2][7][2][16][16];   // ping-pong, waves 1-7, 28 KB

    // ---- per-thread weights, pinned (opaque defs, no remat) ----
    const int u2 = tid & 63;
    float wih0[DIN], wih1[DIN], whh0[HS], whh1[HS];
#pragma unroll
    for (int k = 0; k < DIN; k++) {
        wih0[k] = W_ih[k*G4 + u2]; wih1[k] = W_ih[k*G4 + u2 + 64];
        asm volatile("" : "+v"(wih0[k]), "+v"(wih1[k]));
    }
#pragma unroll
    for (int k = 0; k < HS; k++) {
        whh0[k] = W_hh[k*G4 + u2]; whh1[k] = W_hh[k*G4 + u2 + 64];
        asm volatile("" : "+v"(whh0[k]), "+v"(whh1[k]));
    }
    const float bu0 = bias[u2], bu1 = bias[u2 + 64];

    // P1b/P3 mapping: thread = (node nq = tid>>5, hidden hq = tid&31) — wave-local
    const int hq = tid & 31;
    const int nq = tid >> 5;
    const float bqv = b_q[hq];
    const float wdv = W_d[hq];
    const float bdv = b_d[0];
    float c_reg = 0.0f;               // cell state in a register (ring path)

    // W_q column for this thread's hq, pinned in VGPRs (P1b register FMAs)
    float wqr[HS];
#pragma unroll
    for (int k = 0; k < HS; k++) {
        wqr[k] = W_q[k*HS + hq];
        asm volatile("" : "+v"(wqr[k]));
    }

    // q_pack dword slot for lanes<32 (nodes 2wv,2wv+1 at h=lane):
    //   d = (h>>4)*128 + ((h&15)|((wv>>2)<<4))*4 + (wv&3)
    const int qp_dw = (lane >> 4) * 128 + (((lane & 15) | ((wv >> 2) << 4)) << 2) + (wv & 3);

    // chunk split for waves 1-7: 12,12,12,11,11,11,10 (sum 79)
    int cbeg = 0, nch = 0;
    if (wv >= 1 && wv <= 3)      { cbeg = (wv - 1) * 12;      nch = 12; }
    else if (wv >= 4 && wv <= 6) { cbeg = 36 + (wv - 4) * 11; nch = 11; }
    else if (wv == 7)            { cbeg = 69;                 nch = 10; }
    // producers for this wave's chunks: [2*cbeg, 2*(cbeg+nch)) capped at NBLK
    const int pollbase = 2 * cbeg;
    const int pollcnt  = (wv == 0) ? 0
                       : ((2 * (cbeg + nch) < NBLK ? 2 * (cbeg + nch) : NBLK) - pollbase);
    const unsigned* pollf = flags + (size_t)(pollbase + (lane < pollcnt ? lane : 0)) * FLAGSTRIDE;
    const bool dopoll = (wv >= 1) && (lane < pollcnt);

    // x ownership (ring): wave w>=1 stages nodes 2w,2w+1; waves 1,2 also 0,1
    int xnode = -1, xk = lane & 15;
    if (wv >= 1 && lane < 32)                   xnode = 2*wv + (lane >> 4);
    else if ((wv == 1 || wv == 2) && lane < 48) xnode = wv - 1;
    const int xgn = base + xnode;
    const bool xok = (xnode >= 0) && (xgn < BSN);

    // ---- stage adj to LDS once, in MFMA-A-fragment order ----
    {
        const int n16_per_row = KPAD / 8;           // 316 uint4 per row
        for (int i = tid; i < ROWS * n16_per_row; i += NTHR) {
            int r = i / n16_per_row, o = i - r * n16_per_row;
            int c = o >> 2, kb = o & 3;
            *(uint4*)(adj_lds + (size_t)c * 512 + (size_t)(kb * 16 + r) * 8) =
                ((const uint4*)(adj_bf + (size_t)(base + r) * KPAD))[o];
        }
    }
    for (int i = tid; i < ROWS * HPAD; i += NTHR) {
        (&h_lds[0][0])[i] = 0.0f;
        (&c_lds[0][0])[i] = 0.0f;
    }
    __syncthreads();

    // gates helper: computes both gate halves for node nn (reads x_lds/h_lds)
    auto do_gates = [&](int nn) {
        float a0 = bu0, a1 = bu1;
#pragma unroll
        for (int k4 = 0; k4 < DIN/4; k4++) {
            float4 xv = *(const float4*)&x_lds[nn][k4*4];
            a0 = fmaf(xv.x, wih0[k4*4+0], a0); a1 = fmaf(xv.x, wih1[k4*4+0], a1);
            a0 = fmaf(xv.y, wih0[k4*4+1], a0); a1 = fmaf(xv.y, wih1[k4*4+1], a1);
            a0 = fmaf(xv.z, wih0[k4*4+2], a0); a1 = fmaf(xv.z, wih1[k4*4+2], a1);
            a0 = fmaf(xv.w, wih0[k4*4+3], a0); a1 = fmaf(xv.w, wih1[k4*4+3], a1);
        }
#pragma unroll
        for (int k4 = 0; k4 < HS/4; k4++) {
            float4 hv = *(const float4*)&h_lds[nn][k4*4];
            a0 = fmaf(hv.x, whh0[k4*4+0], a0); a1 = fmaf(hv.x, whh1[k4*4+0], a1);
            a0 = fmaf(hv.y, whh0[k4*4+1], a0); a1 = fmaf(hv.y, whh1[k4*4+1], a1);
            a0 = fmaf(hv.z, whh0[k4*4+2], a0); a1 = fmaf(hv.z, whh1[k4*4+2], a1);
            a0 = fmaf(hv.w, whh0[k4*4+3], a0); a1 = fmaf(hv.w, whh1[k4*4+3], a1);
        }
        gates_lds[nn][u2]      = sigmoid_fast(a0);
        gates_lds[nn][u2 + 64] = (u2 < HS) ? tanh_fast(a1) : sigmoid_fast(a1);
    };

    // P1b core: a = h_lds[nq][:] . wqr + b_q (register weights)
    auto p1b_acc = [&]() -> float {
        float a = bqv;
#pragma unroll
        for (int k4 = 0; k4 < HS/4; k4++) {
            float4 hv = *(const float4*)&h_lds[nq][k4*4];
            a = fmaf(hv.x, wqr[k4*4+0], a);
            a = fmaf(hv.y, wqr[k4*4+1], a);
            a = fmaf(hv.z, wqr[k4*4+2], a);
            a = fmaf(hv.w, wqr[k4*4+3], a);
        }
        return a;
    };

    if constexpr (RING) {
        // x prefetch for t = 0
        float xreg = xok ? x[(size_t)xgn * (TT*DIN) + xk] : 0.0f;

        // publish constants (wave0): block b -> chunk c=b>>1, half=b&1
        const int pc    = blk >> 1;
        const int phalf = blk & 1;
        const int preg  = lane >> 5;       // region 0/1
        const int pidx  = lane & 31;

        for (int t = 0; t < TT; t++) {
            const unsigned phase = (unsigned)(t + 1);
            const ushort_t* qslice = qT + (size_t)t * QT_SLICE;

            // ---- P1b: q_t = tanh(h_{t-1} @ W_q + b_q), shfl-packed bf16 ----
            {
                float qv = tanh_fast(p1b_acc());
                float qp = __shfl_xor(qv, 32);   // partner node's q (same h)
                if (lane < 32) {
                    unsigned val = (unsigned)f2bf(qv) | ((unsigned)f2bf(qp) << 16);
                    ((unsigned*)q_pack)[qp_dw] = val;
                }
            }
            __syncthreads();   // barrier A: q_pack complete; orders prior P3 writes

            if (wv == 0) {
                // ---- publish: 1 ds_read_b128 + 2 agent stores + drain + flag
                //      (drain KEPT: R4/R9 proved it prevents LLC line churn) ----
                union { bf16x8 v; u64_t u[2]; } fr;
                fr.v = *(const bf16x8*)(q_pack + preg * 256 + pidx * 8);
                u64_t* dst = (u64_t*)((ushort_t*)qslice + (size_t)preg * REGUS
                                      + (size_t)pc * 512 + phalf * 256 + pidx * 8);
                __hip_atomic_store(dst,     fr.u[0], __ATOMIC_RELAXED, __HIP_MEMORY_SCOPE_AGENT);
                __hip_atomic_store(dst + 1, fr.u[1], __ATOMIC_RELAXED, __HIP_MEMORY_SCOPE_AGENT);
                asm volatile("s_waitcnt vmcnt(0)" ::: "memory");
                if (lane == 0) {
                    __hip_atomic_store(flags + blk * FLAGSTRIDE, phase,
                                       __ATOMIC_RELAXED, __HIP_MEMORY_SCOPE_AGENT);
                }
                // ---- idle slot: flush previous 16-step out window ----
                if (t >= 16 && (t & 15) == 0) {
                    const int node = lane >> 2, qtr = lane & 3;
                    const int gn = base + node;
                    if (gn < BSN) {
                        *(float4*)(out + (size_t)gn * TT + (t - 16) + qtr * 4) =
                            *(const float4*)&out_lds[node][qtr * 4];
                    }
                }
            } else {
                // ---- x_lds write from prefetched register (wave-local) ----
                if (xnode >= 0) x_lds[xnode][xk] = xok ? xreg : 0.0f;

                // ---- poll FIRST, dual-slot pipelined ----
                if (dopoll) {
                    unsigned a = QLOAD(pollf);
                    unsigned b = QLOAD(pollf);
                    while (a < phase) { a = b; b = QLOAD(pollf); }
                }
                asm volatile("" ::: "memory");   // q loads stay below the poll

                // ---- P2: q loads -> [x prefetch + gates under RTT] -> MFMA ----
                floatx4 acc0 = {0.f,0.f,0.f,0.f}, acc1 = {0.f,0.f,0.f,0.f};
                const int mcol = lane & 15;
                const int kb   = lane >> 4;
                const ushort_t* afrag = adj_lds + (size_t)lane * 8;
                const ushort_t* q0 = qslice + (size_t)lane * 8;
                const ushort_t* q1 = qslice + (size_t)REGUS + (size_t)lane * 8;
                auto mid = [&]() {
                    const int tn = (t + 1 < TT) ? (t + 1) : (TT - 1);
                    if (xok) xreg = x[(size_t)xgn * (TT*DIN) + (size_t)tn * DIN + xk];
                    do_gates(2*wv);
                    do_gates(2*wv + 1);
                    if (wv <= 2) do_gates(wv - 1);   // cover wave 0's nodes
                };
                if (wv <= 3)      p2_gates<12>(afrag, q0, q1, cbeg, mid, acc0, acc1);
                else if (wv <= 6) p2_gates<11>(afrag, q0, q1, cbeg, mid, acc0, acc1);
                else              p2_gates<10>(afrag, q0, q1, cbeg, mid, acc0, acc1);
#pragma unroll
                for (int r = 0; r < 4; r++) {
                    part[t & 1][wv - 1][0][kb*4 + r][mcol] = acc0[r];
                    part[t & 1][wv - 1][1][kb*4 + r][mcol] = acc1[r];
                }
            }
            __syncthreads();   // RAW: part[]/gates (P2 -> P3)

            // ---- P3: cell/hidden update + buffered out head ----
            {
                const int ntile = hq >> 4, col = hq & 15;
                float agg = 0.0f;
#pragma unroll
                for (int j = 0; j < 7; j++) agg += part[t & 1][j][ntile][nq][col];
                float iv = gates_lds[nq][hq];
                float fv = gates_lds[nq][HS + hq];
                float gv = gates_lds[nq][2*HS + hq];
                float ov = gates_lds[nq][3*HS + hq];
                float cv = fv * (c_reg + agg) + iv * gv;
                float hvv = ov * tanh_fast(cv);
                c_reg = cv;
                h_lds[nq][hq] = hvv;
                float p = hvv * wdv;
                p += __shfl_xor(p, 16);
                p += __shfl_xor(p, 8);
                p += __shfl_xor(p, 4);
                p += __shfl_xor(p, 2);
                p += __shfl_xor(p, 1);
                if (hq == 0) out_lds[nq][t & 15] = p + bdv;
            }
        }
        // ---- final out window [TT-16, TT) ----
        __syncthreads();
        if (wv == 0) {
            const int node = lane >> 2, qtr = lane & 3;
            const int gn = base + node;
            if (gn < BSN) {
                *(float4*)(out + (size_t)gn * TT + (TT - 16) + qtr * 4) =
                    *(const float4*)&out_lds[node][qtr * 4];
            }
        }
    } else {
        // ================= parity fallback: R2-proven flag structure =================
        for (int t = 0; t < TT; t++) {
            const unsigned phase = (unsigned)(t + 1);
            ushort_t* qbuf = qT + (size_t)(t & 1) * QT_SLICE;

            q_lds[nq][hq] = tanh_fast(p1b_acc());
            __syncthreads();

            if (tid < 256) {
                const int h0 = tid >> 3;
                const int pr = tid & 7;
                unsigned val = (unsigned)f2bf(q_lds[2*pr][h0])
                             | ((unsigned)f2bf(q_lds[2*pr + 1][h0]) << 16);
                unsigned* p = (unsigned*)(qbuf + (size_t)h0 * KPAD + base) + pr;
                __hip_atomic_store(p, val, __ATOMIC_RELAXED, __HIP_MEMORY_SCOPE_AGENT);
            }
            if (lane < 32) {
                const int node = 2*wv + (lane >> 4), k = lane & 15;
                const int gn = base + node;
                x_lds[node][k] = (gn < BSN) ? x[(size_t)gn * (TT*DIN) + (size_t)t*DIN + k] : 0.0f;
            }
            do_gates(2*wv);
            do_gates(2*wv + 1);
            asm volatile("s_waitcnt vmcnt(0)" ::: "memory");
            __syncthreads();
            if (tid == 0) {
                __hip_atomic_store(flags + blk * FLAGSTRIDE, phase,
                                   __ATOMIC_RELAXED, __HIP_MEMORY_SCOPE_AGENT);
            }
            if (tid < NBLK) {
                const unsigned* f = flags + tid * FLAGSTRIDE;
                while (QLOAD(f) < phase) {}
            }
            __syncthreads();

            {
                floatx4 acc0 = {0.f,0.f,0.f,0.f}, acc1 = {0.f,0.f,0.f,0.f};
                const int mcol = lane & 15;
                const int kb   = lane >> 4;
                const ushort_t* afrag = adj_lds + (size_t)lane * 8;   // fragment order
                const u64_t* q0 = (const u64_t*)(qbuf + (size_t)mcol        * KPAD) + kb*2;
                const u64_t* q1 = (const u64_t*)(qbuf + (size_t)(mcol + 16) * KPAD) + kb*2;
                const int cb2 = wv * 10;
                const int ce2 = (cb2 + 10 < NCHUNK) ? cb2 + 10 : NCHUNK;
                for (int c = cb2; c < ce2; c++) {
                    bf16x8 av = *(const bf16x8*)(afrag + (size_t)c * 512);
                    union { u64_t u[2]; bf16x8 v; } b0, b1;
                    b0.u[0] = QLOAD(q0 + c*8);
                    b0.u[1] = QLOAD(q0 + c*8 + 1);
                    b1.u[0] = QLOAD(q1 + c*8);
                    b1.u[1] = QLOAD(q1 + c*8 + 1);
                    acc0 = __builtin_amdgcn_mfma_f32_16x16x32_bf16(av, b0.v, acc0, 0, 0, 0);
                    acc1 = __builtin_amdgcn_mfma_f32_16x16x32_bf16(av, b1.v, acc1, 0, 0, 0);
                }
                // flat per-wave slots in part[] (8 waves x 512 floats)
                float* pw = &part[0][0][0][0][0] + (size_t)wv * 2 * 16 * 16;
#pragma unroll
                for (int r = 0; r < 4; r++) {
                    pw[(0*16 + kb*4 + r) * 16 + mcol] = acc0[r];
                    pw[(1*16 + kb*4 + r) * 16 + mcol] = acc1[r];
                }
            }
            __syncthreads();

            {
                const int ntile = hq >> 4, col = hq & 15;
                float agg = 0.0f;
                const float* pbase = &part[0][0][0][0][0];
#pragma unroll
                for (int w = 0; w < 8; w++) {
                    agg += pbase[(size_t)w * 2 * 16 * 16 + (ntile*16 + nq) * 16 + col];
                }
                float iv = gates_lds[nq][hq];
                float fv = gates_lds[nq][HS + hq];
                float gv = gates_lds[nq][2*HS + hq];
                float ov = gates_lds[nq][3*HS + hq];
                float cv = fv * (c_lds[nq][hq] + agg) + iv * gv;
                float hv = ov * tanh_fast(cv);
                c_lds[nq][hq] = cv;
                h_lds[nq][hq] = hv;
                float p = hv * wdv;
                p += __shfl_xor(p, 16);
                p += __shfl_xor(p, 8);
                p += __shfl_xor(p, 4);
                p += __shfl_xor(p, 2);
                p += __shfl_xor(p, 1);
                if (hq == 0) {
                    int gn = base + nq;
                    if (gn < BSN) out[(size_t)gn * TT + t] = p + bdv;
                }
            }
            __syncthreads();
        }
    }
}

extern "C" void kernel_launch(void* const* d_in, const int* in_sizes, int n_in,
                              void* d_out, int out_size, void* d_ws, size_t ws_size,
                              hipStream_t stream) {
    const float* x    = (const float*)d_in[0];
    const float* adj  = (const float*)d_in[1];
    const float* W_ih = (const float*)d_in[2];
    const float* W_hh = (const float*)d_in[3];
    const float* bias = (const float*)d_in[4];
    const float* W_q  = (const float*)d_in[5];
    const float* b_q  = (const float*)d_in[6];
    const float* W_d  = (const float*)d_in[7];
    const float* b_d  = (const float*)d_in[8];
    float* out = (float*)d_out;

    unsigned* flags = (unsigned*)((char*)d_ws + WS_FLAGS_OFF);
    ushort_t* adj_bf = (ushort_t*)((char*)d_ws + WS_ADJ_OFF);
    ushort_t* qT = (ushort_t*)((char*)d_ws + WS_QT_OFF);

    const bool ring = (ws_size >= WS_NEED_RING);   // constant across calls -> graph-safe

    // prep also pre-writes out=12345 (sentinel): if the cooperative launch is
    // rejected, absmax flags it.
    hipLaunchKernelGGL(prep, dim3(2048), dim3(256), 0, stream, adj, adj_bf, qT, flags,
                       out, out_size);

    const ushort_t* adj_bf_c = adj_bf;
    void* args[] = {
        (void*)&x, (void*)&W_ih, (void*)&W_hh, (void*)&bias, (void*)&W_q,
        (void*)&b_q, (void*)&W_d, (void*)&b_d, (void*)&adj_bf_c, (void*)&qT,
        (void*)&flags, (void*)&out
    };
    if (ring) {
        hipLaunchCooperativeKernel((void*)&rgcn_main<true>, dim3(NBLK), dim3(NTHR),
                                   args, 0, stream);
    } else {
        hipLaunchCooperativeKernel((void*)&rgcn_main<false>, dim3(NBLK), dim3(NTHR),
                                   args, 0, stream);
    }
}

// Round 11
// 1786.326 us; speedup vs baseline: 1.9396x; 1.9396x over previous
//
#include <hip/hip_runtime.h>
#include <hip/hip_bf16.h>

// Problem constants
#define BSN   2500   // nodes
#define TT    400    // time steps
#define DIN   16     // input dim
#define HS    32     // hidden dim
#define G4    128    // 4*HS
#define NBLK  157    // blocks (16 rows each)
#define NTHR  512    // 8 waves: 2 waves/SIMD for latency overlap
#define ROWS  16     // nodes per block (MFMA M-tile)
#define MPAD  (NBLK * ROWS)   // 2512 padded rows
#define KPAD  2528            // 79*32 (proven adj layout)
#define NCHUNK 79
#define HPAD  36              // fp32 LDS row pad
#define FLAGSTRIDE 16         // uints between flags (64 B)

// Fragment-ordered q slice (ring mode):
//   region r (r=0: h rows 0-15, r=1: h rows 16-31), chunk c (32 nodes),
//   byte addr = r*REGBYTES + c*1024 + lane*16 holds the 16 B MFMA-B fragment
//   for lane `lane` of chunk c. Producer block b (c=b>>1, half=b&1) owns the
//   contiguous 512 B [c*1024+half*512, +512) of each region.
#define REGUS   (NCHUNK * 512)          // region size in ushorts (40448)

// workspace layout (bytes) — identical to prior rounds
#define WS_FLAGS_OFF  0
#define WS_ADJ_OFF    16384
#define WS_ADJ_BYTES  ((size_t)MPAD * KPAD * 2)
#define WS_QT_OFF     (WS_ADJ_OFF + WS_ADJ_BYTES)
#define QT_SLICE      ((size_t)HS * KPAD)
#define WS_NEED_RING  (WS_QT_OFF + (size_t)TT * QT_SLICE * 2)   // ~77.4 MB

typedef __attribute__((ext_vector_type(8))) __bf16 bf16x8;
typedef __attribute__((ext_vector_type(4))) float floatx4;
typedef unsigned short ushort_t;
typedef unsigned long long u64_t;

__device__ __forceinline__ float sigmoid_fast(float v) {
    return 1.0f / (1.0f + __expf(-v));
}
__device__ __forceinline__ float tanh_fast(float v) {
    float e = __expf(2.0f * v);
    return 1.0f - 2.0f / (e + 1.0f);
}
__device__ __forceinline__ ushort_t f2bf(float f) {
    union { float f; unsigned u; } x; x.f = f;
    unsigned r = x.u + 0x7fffu + ((x.u >> 16) & 1u);  // RNE
    return (ushort_t)(r >> 16);
}

// Per-launch prep (d_ws re-poisoned 0xAA before every timed launch).
// Also pre-writes out = 12345.0 (sentinel): if the cooperative launch below is
// rejected at submit time, absmax ~1.23e4 flags it (vs 3.9e-3 "correct").
__global__ void prep(const float* __restrict__ adj, ushort_t* __restrict__ adj_bf,
                     ushort_t* __restrict__ qT, unsigned* __restrict__ flags,
                     float* __restrict__ out, int out_n) {
    const size_t idx0 = (size_t)blockIdx.x * blockDim.x + threadIdx.x;
    const size_t stride = (size_t)gridDim.x * blockDim.x;
    const size_t total = (size_t)MPAD * KPAD;
    for (size_t idx = idx0; idx < total; idx += stride) {
        int r = (int)(idx / KPAD);
        int k = (int)(idx - (size_t)r * KPAD);
        float v = (r < BSN && k < BSN) ? adj[(size_t)r * BSN + k] : 0.0f;
        adj_bf[idx] = f2bf(v);
    }
    for (size_t idx = idx0; idx < 2 * QT_SLICE; idx += stride) qT[idx] = 0;
    for (size_t idx = idx0; idx < (size_t)out_n; idx += stride) out[idx] = 12345.0f;
    if (idx0 < NBLK * FLAGSTRIDE) flags[idx0] = 0;
}

#define QLOAD(p) __hip_atomic_load((p), __ATOMIC_RELAXED, __HIP_MEMORY_SCOPE_AGENT)

// P2, fragment layout on BOTH operands: chunk c's A-fragment (adj, LDS) and
// B-fragments (q, LLC) for this lane live at base + c*512 ushorts. Every
// LDS/global access is a 64-lane x 16 B sequential burst — conflict-free.
// Loads are issued as one batch (R6/R8-proven; R7's incremental and R10's
// fenced variants both regressed).
template<int NC>
__device__ __forceinline__ void p2_frag(const ushort_t* __restrict__ afrag,
                                        const ushort_t* __restrict__ q0,
                                        const ushort_t* __restrict__ q1,
                                        const int cbeg,
                                        floatx4& acc0, floatx4& acc1) {
    bf16x8 b0[NC], b1[NC];
#pragma unroll
    for (int i = 0; i < NC; i++) {
        b0[i] = *(const bf16x8*)(q0 + (size_t)(cbeg + i) * 512);
        b1[i] = *(const bf16x8*)(q1 + (size_t)(cbeg + i) * 512);
    }
#pragma unroll
    for (int i = 0; i < NC; i++) {
        bf16x8 av = *(const bf16x8*)(afrag + (size_t)(cbeg + i) * 512);
        acc0 = __builtin_amdgcn_mfma_f32_16x16x32_bf16(av, b0[i], acc0, 0, 0, 0);
        acc1 = __builtin_amdgcn_mfma_f32_16x16x32_bf16(av, b1[i], acc1, 0, 0, 0);
    }
}

// Persistent cooperative kernel, 512 threads (8 waves), block b owns nodes
// [16b,16b+16).
// R11 = R8 verbatim (proven 1640 us steady: flag protocol + producer drain
// kept — R4/R9/R10 proved every alternative regresses) + ONE load-balance
// fix: the extra gates for nodes 0,1 move from waves 1,2 (12 P2 chunks =
// heaviest) to waves 6,7 (11/10 chunks = lightest), with their x staging.
// Per-wave load at RAW: w1-3: 12ch+2g, w4-5: 11+2, w6: 11+3, w7: 10+3.
template<bool RING>
__global__ void __launch_bounds__(NTHR, 2) rgcn_main(
    const float* __restrict__ x,      // [BSN][TT][DIN]
    const float* __restrict__ W_ih,   // [DIN][G4]
    const float* __restrict__ W_hh,   // [HS][G4]
    const float* __restrict__ bias,   // [G4]
    const float* __restrict__ W_q,    // [HS][HS]
    const float* __restrict__ b_q,    // [HS]
    const float* __restrict__ W_d,    // [HS]
    const float* __restrict__ b_d,    // [1]
    const ushort_t* __restrict__ adj_bf, // [MPAD][KPAD] bf16
    ushort_t* __restrict__ qT,        // ring: [TT] fragment slices; parity: [2][HS][KPAD]
    unsigned* __restrict__ flags,     // [NBLK] generation flags, FLAGSTRIDE apart
    float* __restrict__ out)          // [BSN][TT]
{
    const int tid  = threadIdx.x;
    const int blk  = blockIdx.x;
    const int base = blk * ROWS;
    const int wv   = tid >> 6;        // wave 0..7
    const int lane = tid & 63;

    __shared__ __align__(16) ushort_t adj_lds[NCHUNK * 512];  // 79 KB, fragment order
    __shared__ __align__(16) ushort_t q_pack[512];            // 1 KB publish staging (ring)
    __shared__ __align__(16) float x_lds[ROWS][DIN];
    __shared__ __align__(16) float h_lds[ROWS][HPAD];
    __shared__ __align__(16) float c_lds[ROWS][HPAD];         // parity path only
    __shared__ __align__(16) float q_lds[ROWS][HPAD];         // parity path only
    __shared__ __align__(16) float out_lds[ROWS][16];         // 16-step out buffer
    __shared__ float gates_lds[ROWS][G4];
    __shared__ float part[2][7][2][16][16];   // ping-pong, waves 1-7, 28 KB

    // ---- per-thread weights, pinned (opaque defs, no remat) ----
    const int u2 = tid & 63;
    float wih0[DIN], wih1[DIN], whh0[HS], whh1[HS];
#pragma unroll
    for (int k = 0; k < DIN; k++) {
        wih0[k] = W_ih[k*G4 + u2]; wih1[k] = W_ih[k*G4 + u2 + 64];
        asm volatile("" : "+v"(wih0[k]), "+v"(wih1[k]));
    }
#pragma unroll
    for (int k = 0; k < HS; k++) {
        whh0[k] = W_hh[k*G4 + u2]; whh1[k] = W_hh[k*G4 + u2 + 64];
        asm volatile("" : "+v"(whh0[k]), "+v"(whh1[k]));
    }
    const float bu0 = bias[u2], bu1 = bias[u2 + 64];

    // P1b/P3 mapping: thread = (node nq = tid>>5, hidden hq = tid&31) — wave-local
    const int hq = tid & 31;
    const int nq = tid >> 5;
    const float bqv = b_q[hq];
    const float wdv = W_d[hq];
    const float bdv = b_d[0];
    float c_reg = 0.0f;               // cell state in a register (ring path)

    // W_q column for this thread's hq, pinned in VGPRs (P1b register FMAs)
    float wqr[HS];
#pragma unroll
    for (int k = 0; k < HS; k++) {
        wqr[k] = W_q[k*HS + hq];
        asm volatile("" : "+v"(wqr[k]));
    }

    // q_pack dword slot for lanes<32 (nodes 2wv,2wv+1 at h=lane):
    //   d = (h>>4)*128 + ((h&15)|((wv>>2)<<4))*4 + (wv&3)
    const int qp_dw = (lane >> 4) * 128 + (((lane & 15) | ((wv >> 2) << 4)) << 2) + (wv & 3);

    // chunk split for waves 1-7: 12,12,12,11,11,11,10 (sum 79)
    int cbeg = 0, nch = 0;
    if (wv >= 1 && wv <= 3)      { cbeg = (wv - 1) * 12;      nch = 12; }
    else if (wv >= 4 && wv <= 6) { cbeg = 36 + (wv - 4) * 11; nch = 11; }
    else if (wv == 7)            { cbeg = 69;                 nch = 10; }
    // producers for this wave's chunks: [2*cbeg, 2*(cbeg+nch)) capped at NBLK
    const int pollbase = 2 * cbeg;
    const int pollcnt  = (wv == 0) ? 0
                       : ((2 * (cbeg + nch) < NBLK ? 2 * (cbeg + nch) : NBLK) - pollbase);
    const unsigned* pollf = flags + (size_t)(pollbase + (lane < pollcnt ? lane : 0)) * FLAGSTRIDE;
    const bool dopoll = (wv >= 1) && (lane < pollcnt);

    // x ownership (ring): wave w>=1 stages nodes 2w,2w+1; waves 6,7 also
    // stage nodes 0,1 (load-balance: waves 1-3 carry 12 P2 chunks, 6,7 only
    // 11/10 — the extra gate belongs on the lightest waves)
    int xnode = -1, xk = lane & 15;
    if (wv >= 1 && lane < 32)                   xnode = 2*wv + (lane >> 4);
    else if ((wv == 6 || wv == 7) && lane < 48) xnode = wv - 6;
    const int xgn = base + xnode;
    const bool xok = (xnode >= 0) && (xgn < BSN);

    // ---- stage adj to LDS once, in MFMA-A-fragment order ----
    {
        const int n16_per_row = KPAD / 8;           // 316 uint4 per row
        for (int i = tid; i < ROWS * n16_per_row; i += NTHR) {
            int r = i / n16_per_row, o = i - r * n16_per_row;
            int c = o >> 2, kb = o & 3;
            *(uint4*)(adj_lds + (size_t)c * 512 + (size_t)(kb * 16 + r) * 8) =
                ((const uint4*)(adj_bf + (size_t)(base + r) * KPAD))[o];
        }
    }
    for (int i = tid; i < ROWS * HPAD; i += NTHR) {
        (&h_lds[0][0])[i] = 0.0f;
        (&c_lds[0][0])[i] = 0.0f;
    }
    __syncthreads();

    // gates helper: computes both gate halves for node nn (reads x_lds/h_lds)
    auto do_gates = [&](int nn) {
        float a0 = bu0, a1 = bu1;
#pragma unroll
        for (int k4 = 0; k4 < DIN/4; k4++) {
            float4 xv = *(const float4*)&x_lds[nn][k4*4];
            a0 = fmaf(xv.x, wih0[k4*4+0], a0); a1 = fmaf(xv.x, wih1[k4*4+0], a1);
            a0 = fmaf(xv.y, wih0[k4*4+1], a0); a1 = fmaf(xv.y, wih1[k4*4+1], a1);
            a0 = fmaf(xv.z, wih0[k4*4+2], a0); a1 = fmaf(xv.z, wih1[k4*4+2], a1);
            a0 = fmaf(xv.w, wih0[k4*4+3], a0); a1 = fmaf(xv.w, wih1[k4*4+3], a1);
        }
#pragma unroll
        for (int k4 = 0; k4 < HS/4; k4++) {
            float4 hv = *(const float4*)&h_lds[nn][k4*4];
            a0 = fmaf(hv.x, whh0[k4*4+0], a0); a1 = fmaf(hv.x, whh1[k4*4+0], a1);
            a0 = fmaf(hv.y, whh0[k4*4+1], a0); a1 = fmaf(hv.y, whh1[k4*4+1], a1);
            a0 = fmaf(hv.z, whh0[k4*4+2], a0); a1 = fmaf(hv.z, whh1[k4*4+2], a1);
            a0 = fmaf(hv.w, whh0[k4*4+3], a0); a1 = fmaf(hv.w, whh1[k4*4+3], a1);
        }
        gates_lds[nn][u2]      = sigmoid_fast(a0);
        gates_lds[nn][u2 + 64] = (u2 < HS) ? tanh_fast(a1) : sigmoid_fast(a1);
    };

    // P1b core: a = h_lds[nq][:] . wqr + b_q (register weights)
    auto p1b_acc = [&]() -> float {
        float a = bqv;
#pragma unroll
        for (int k4 = 0; k4 < HS/4; k4++) {
            float4 hv = *(const float4*)&h_lds[nq][k4*4];
            a = fmaf(hv.x, wqr[k4*4+0], a);
            a = fmaf(hv.y, wqr[k4*4+1], a);
            a = fmaf(hv.z, wqr[k4*4+2], a);
            a = fmaf(hv.w, wqr[k4*4+3], a);
        }
        return a;
    };

    if constexpr (RING) {
        // x prefetch for t = 0
        float xreg = xok ? x[(size_t)xgn * (TT*DIN) + xk] : 0.0f;

        // publish constants (wave0): block b -> chunk c=b>>1, half=b&1
        const int pc    = blk >> 1;
        const int phalf = blk & 1;
        const int preg  = lane >> 5;       // region 0/1
        const int pidx  = lane & 31;

        for (int t = 0; t < TT; t++) {
            const unsigned phase = (unsigned)(t + 1);
            const ushort_t* qslice = qT + (size_t)t * QT_SLICE;

            // ---- P1b: q_t = tanh(h_{t-1} @ W_q + b_q), shfl-packed bf16 ----
            {
                float qv = tanh_fast(p1b_acc());
                float qp = __shfl_xor(qv, 32);   // partner node's q (same h)
                if (lane < 32) {
                    unsigned val = (unsigned)f2bf(qv) | ((unsigned)f2bf(qp) << 16);
                    ((unsigned*)q_pack)[qp_dw] = val;
                }
            }
            __syncthreads();   // barrier A: q_pack complete; orders prior P3 writes

            if (wv == 0) {
                // ---- publish: 1 ds_read_b128 + 2 agent stores + drain + flag
                //      (drain KEPT: R4/R9 proved it prevents LLC line churn) ----
                union { bf16x8 v; u64_t u[2]; } fr;
                fr.v = *(const bf16x8*)(q_pack + preg * 256 + pidx * 8);
                u64_t* dst = (u64_t*)((ushort_t*)qslice + (size_t)preg * REGUS
                                      + (size_t)pc * 512 + phalf * 256 + pidx * 8);
                __hip_atomic_store(dst,     fr.u[0], __ATOMIC_RELAXED, __HIP_MEMORY_SCOPE_AGENT);
                __hip_atomic_store(dst + 1, fr.u[1], __ATOMIC_RELAXED, __HIP_MEMORY_SCOPE_AGENT);
                asm volatile("s_waitcnt vmcnt(0)" ::: "memory");
                if (lane == 0) {
                    __hip_atomic_store(flags + blk * FLAGSTRIDE, phase,
                                       __ATOMIC_RELAXED, __HIP_MEMORY_SCOPE_AGENT);
                }
                // ---- idle slot: flush previous 16-step out window ----
                if (t >= 16 && (t & 15) == 0) {
                    const int node = lane >> 2, qtr = lane & 3;
                    const int gn = base + node;
                    if (gn < BSN) {
                        *(float4*)(out + (size_t)gn * TT + (t - 16) + qtr * 4) =
                            *(const float4*)&out_lds[node][qtr * 4];
                    }
                }
            } else {
                // ---- shadow: x_lds write (prefetched) + next prefetch + gates ----
                if (xnode >= 0) {
                    x_lds[xnode][xk] = xok ? xreg : 0.0f;
                    const int tn = (t + 1 < TT) ? (t + 1) : (TT - 1);
                    if (xok) xreg = x[(size_t)xgn * (TT*DIN) + (size_t)tn * DIN + xk];
                }
                do_gates(2*wv);
                do_gates(2*wv + 1);
                if (wv >= 6) do_gates(wv - 6);   // cover wave 0's nodes (lightest waves)
            }

            // ---- per-wave poll, dual-slot pipelined (2 loads in flight) ----
            if (dopoll) {
                unsigned a = QLOAD(pollf);
                unsigned b = QLOAD(pollf);
                while (a < phase) { a = b; b = QLOAD(pollf); }
            }

            // ---- P2 (waves 1-7): agg = adj(LDS frag) @ q(LLC frag) ----
            if (wv >= 1) {
                floatx4 acc0 = {0.f,0.f,0.f,0.f}, acc1 = {0.f,0.f,0.f,0.f};
                const int mcol = lane & 15;
                const int kb   = lane >> 4;
                const ushort_t* afrag = adj_lds + (size_t)lane * 8;
                const ushort_t* q0 = qslice + (size_t)lane * 8;
                const ushort_t* q1 = qslice + (size_t)REGUS + (size_t)lane * 8;
                if (wv <= 3)      p2_frag<12>(afrag, q0, q1, cbeg, acc0, acc1);
                else if (wv <= 6) p2_frag<11>(afrag, q0, q1, cbeg, acc0, acc1);
                else              p2_frag<10>(afrag, q0, q1, cbeg, acc0, acc1);
#pragma unroll
                for (int r = 0; r < 4; r++) {
                    part[t & 1][wv - 1][0][kb*4 + r][mcol] = acc0[r];
                    part[t & 1][wv - 1][1][kb*4 + r][mcol] = acc1[r];
                }
            }
            __syncthreads();   // RAW: part[]/gates (P2 -> P3)

            // ---- P3: cell/hidden update + buffered out head ----
            {
                const int ntile = hq >> 4, col = hq & 15;
                float agg = 0.0f;
#pragma unroll
                for (int j = 0; j < 7; j++) agg += part[t & 1][j][ntile][nq][col];
                float iv = gates_lds[nq][hq];
                float fv = gates_lds[nq][HS + hq];
                float gv = gates_lds[nq][2*HS + hq];
                float ov = gates_lds[nq][3*HS + hq];
                float cv = fv * (c_reg + agg) + iv * gv;
                float hvv = ov * tanh_fast(cv);
                c_reg = cv;
                h_lds[nq][hq] = hvv;
                float p = hvv * wdv;
                p += __shfl_xor(p, 16);
                p += __shfl_xor(p, 8);
                p += __shfl_xor(p, 4);
                p += __shfl_xor(p, 2);
                p += __shfl_xor(p, 1);
                if (hq == 0) out_lds[nq][t & 15] = p + bdv;
            }
        }
        // ---- final out window [TT-16, TT) ----
        __syncthreads();
        if (wv == 0) {
            const int node = lane >> 2, qtr = lane & 3;
            const int gn = base + node;
            if (gn < BSN) {
                *(float4*)(out + (size_t)gn * TT + (TT - 16) + qtr * 4) =
                    *(const float4*)&out_lds[node][qtr * 4];
            }
        }
    } else {
        // ================= parity fallback: R2-proven flag structure =================
        for (int t = 0; t < TT; t++) {
            const unsigned phase = (unsigned)(t + 1);
            ushort_t* qbuf = qT + (size_t)(t & 1) * QT_SLICE;

            q_lds[nq][hq] = tanh_fast(p1b_acc());
            __syncthreads();

            if (tid < 256) {
                const int h0 = tid >> 3;
                const int pr = tid & 7;
                unsigned val = (unsigned)f2bf(q_lds[2*pr][h0])
                             | ((unsigned)f2bf(q_lds[2*pr + 1][h0]) << 16);
                unsigned* p = (unsigned*)(qbuf + (size_t)h0 * KPAD + base) + pr;
                __hip_atomic_store(p, val, __ATOMIC_RELAXED, __HIP_MEMORY_SCOPE_AGENT);
            }
            if (lane < 32) {
                const int node = 2*wv + (lane >> 4), k = lane & 15;
                const int gn = base + node;
                x_lds[node][k] = (gn < BSN) ? x[(size_t)gn * (TT*DIN) + (size_t)t*DIN + k] : 0.0f;
            }
            do_gates(2*wv);
            do_gates(2*wv + 1);
            asm volatile("s_waitcnt vmcnt(0)" ::: "memory");
            __syncthreads();
            if (tid == 0) {
                __hip_atomic_store(flags + blk * FLAGSTRIDE, phase,
                                   __ATOMIC_RELAXED, __HIP_MEMORY_SCOPE_AGENT);
            }
            if (tid < NBLK) {
                const unsigned* f = flags + tid * FLAGSTRIDE;
                while (QLOAD(f) < phase) {}
            }
            __syncthreads();

            {
                floatx4 acc0 = {0.f,0.f,0.f,0.f}, acc1 = {0.f,0.f,0.f,0.f};
                const int mcol = lane & 15;
                const int kb   = lane >> 4;
                const ushort_t* afrag = adj_lds + (size_t)lane * 8;   // fragment order
                const u64_t* q0 = (const u64_t*)(qbuf + (size_t)mcol        * KPAD) + kb*2;
                const u64_t* q1 = (const u64_t*)(qbuf + (size_t)(mcol + 16) * KPAD) + kb*2;
                const int cb2 = wv * 10;
                const int ce2 = (cb2 + 10 < NCHUNK) ? cb2 + 10 : NCHUNK;
                for (int c = cb2; c < ce2; c++) {
                    bf16x8 av = *(const bf16x8*)(afrag + (size_t)c * 512);
                    union { u64_t u[2]; bf16x8 v; } b0, b1;
                    b0.u[0] = QLOAD(q0 + c*8);
                    b0.u[1] = QLOAD(q0 + c*8 + 1);
                    b1.u[0] = QLOAD(q1 + c*8);
                    b1.u[1] = QLOAD(q1 + c*8 + 1);
                    acc0 = __builtin_amdgcn_mfma_f32_16x16x32_bf16(av, b0.v, acc0, 0, 0, 0);
                    acc1 = __builtin_amdgcn_mfma_f32_16x16x32_bf16(av, b1.v, acc1, 0, 0, 0);
                }
                // flat per-wave slots in part[] (8 waves x 512 floats)
                float* pw = &part[0][0][0][0][0] + (size_t)wv * 2 * 16 * 16;
#pragma unroll
                for (int r = 0; r < 4; r++) {
                    pw[(0*16 + kb*4 + r) * 16 + mcol] = acc0[r];
                    pw[(1*16 + kb*4 + r) * 16 + mcol] = acc1[r];
                }
            }
            __syncthreads();

            {
                const int ntile = hq >> 4, col = hq & 15;
                float agg = 0.0f;
                const float* pbase = &part[0][0][0][0][0];
#pragma unroll
                for (int w = 0; w < 8; w++) {
                    agg += pbase[(size_t)w * 2 * 16 * 16 + (ntile*16 + nq) * 16 + col];
                }
                float iv = gates_lds[nq][hq];
                float fv = gates_lds[nq][HS + hq];
                float gv = gates_lds[nq][2*HS + hq];
                float ov = gates_lds[nq][3*HS + hq];
                float cv = fv * (c_lds[nq][hq] + agg) + iv * gv;
                float hv = ov * tanh_fast(cv);
                c_lds[nq][hq] = cv;
                h_lds[nq][hq] = hv;
                float p = hv * wdv;
                p += __shfl_xor(p, 16);
                p += __shfl_xor(p, 8);
                p += __shfl_xor(p, 4);
                p += __shfl_xor(p, 2);
                p += __shfl_xor(p, 1);
                if (hq == 0) {
                    int gn = base + nq;
                    if (gn < BSN) out[(size_t)gn * TT + t] = p + bdv;
                }
            }
            __syncthreads();
        }
    }
}

extern "C" void kernel_launch(void* const* d_in, const int* in_sizes, int n_in,
                              void* d_out, int out_size, void* d_ws, size_t ws_size,
                              hipStream_t stream) {
    const float* x    = (const float*)d_in[0];
    const float* adj  = (const float*)d_in[1];
    const float* W_ih = (const float*)d_in[2];
    const float* W_hh = (const float*)d_in[3];
    const float* bias = (const float*)d_in[4];
    const float* W_q  = (const float*)d_in[5];
    const float* b_q  = (const float*)d_in[6];
    const float* W_d  = (const float*)d_in[7];
    const float* b_d  = (const float*)d_in[8];
    float* out = (float*)d_out;

    unsigned* flags = (unsigned*)((char*)d_ws + WS_FLAGS_OFF);
    ushort_t* adj_bf = (ushort_t*)((char*)d_ws + WS_ADJ_OFF);
    ushort_t* qT = (ushort_t*)((char*)d_ws + WS_QT_OFF);

    const bool ring = (ws_size >= WS_NEED_RING);   // constant across calls -> graph-safe

    // prep also pre-writes out=12345 (sentinel): if the cooperative launch is
    // rejected, absmax flags it.
    hipLaunchKernelGGL(prep, dim3(2048), dim3(256), 0, stream, adj, adj_bf, qT, flags,
                       out, out_size);

    const ushort_t* adj_bf_c = adj_bf;
    void* args[] = {
        (void*)&x, (void*)&W_ih, (void*)&W_hh, (void*)&bias, (void*)&W_q,
        (void*)&b_q, (void*)&W_d, (void*)&b_d, (void*)&adj_bf_c, (void*)&qT,
        (void*)&flags, (void*)&out
    };
    if (ring) {
        hipLaunchCooperativeKernel((void*)&rgcn_main<true>, dim3(NBLK), dim3(NTHR),
                                   args, 0, stream);
    } else {
        hipLaunchCooperativeKernel((void*)&rgcn_main<false>, dim3(NBLK), dim3(NTHR),
                                   args, 0, stream);
    }
}

// Round 12
// 1729.479 us; speedup vs baseline: 2.0033x; 1.0329x over previous
//
#include <hip/hip_runtime.h>
#include <hip/hip_bf16.h>

// Problem constants
#define BSN   2500   // nodes
#define TT    400    // time steps
#define DIN   16     // input dim
#define HS    32     // hidden dim
#define G4    128    // 4*HS
#define NBLK  157    // blocks (16 rows each)
#define NTHR  512    // 8 waves: 2 waves/SIMD for latency overlap
#define ROWS  16     // nodes per block (MFMA M-tile)
#define MPAD  (NBLK * ROWS)   // 2512 padded rows
#define KPAD  2528            // 79*32 (proven adj layout)
#define NCHUNK 79
#define HPAD  36              // fp32 LDS row pad
#define FLAGSTRIDE 16         // uints between flags (64 B)

// Fragment-ordered q slice (ring mode):
//   region r (r=0: h rows 0-15, r=1: h rows 16-31), chunk c (32 nodes),
//   byte addr = r*REGBYTES + c*1024 + lane*16 holds the 16 B MFMA-B fragment
//   for lane `lane` of chunk c. Producer block b (c=b>>1, half=b&1) owns the
//   contiguous 512 B [c*1024+half*512, +512) of each region.
#define REGUS   (NCHUNK * 512)          // region size in ushorts (40448)

// workspace layout (bytes) — identical to prior rounds
#define WS_FLAGS_OFF  0
#define WS_ADJ_OFF    16384
#define WS_ADJ_BYTES  ((size_t)MPAD * KPAD * 2)
#define WS_QT_OFF     (WS_ADJ_OFF + WS_ADJ_BYTES)
#define QT_SLICE      ((size_t)HS * KPAD)
#define WS_NEED_RING  (WS_QT_OFF + (size_t)TT * QT_SLICE * 2)   // ~77.4 MB

typedef __attribute__((ext_vector_type(8))) __bf16 bf16x8;
typedef __attribute__((ext_vector_type(4))) float floatx4;
typedef unsigned short ushort_t;
typedef unsigned long long u64_t;

__device__ __forceinline__ float sigmoid_fast(float v) {
    return 1.0f / (1.0f + __expf(-v));
}
__device__ __forceinline__ float tanh_fast(float v) {
    float e = __expf(2.0f * v);
    return 1.0f - 2.0f / (e + 1.0f);
}
__device__ __forceinline__ ushort_t f2bf(float f) {
    union { float f; unsigned u; } x; x.f = f;
    unsigned r = x.u + 0x7fffu + ((x.u >> 16) & 1u);  // RNE
    return (ushort_t)(r >> 16);
}

// Per-launch prep (d_ws re-poisoned 0xAA before every timed launch).
// Also pre-writes out = 12345.0 (sentinel): if the cooperative launch below is
// rejected at submit time, absmax ~1.23e4 flags it (vs 3.9e-3 "correct").
__global__ void prep(const float* __restrict__ adj, ushort_t* __restrict__ adj_bf,
                     ushort_t* __restrict__ qT, unsigned* __restrict__ flags,
                     float* __restrict__ out, int out_n) {
    const size_t idx0 = (size_t)blockIdx.x * blockDim.x + threadIdx.x;
    const size_t stride = (size_t)gridDim.x * blockDim.x;
    const size_t total = (size_t)MPAD * KPAD;
    for (size_t idx = idx0; idx < total; idx += stride) {
        int r = (int)(idx / KPAD);
        int k = (int)(idx - (size_t)r * KPAD);
        float v = (r < BSN && k < BSN) ? adj[(size_t)r * BSN + k] : 0.0f;
        adj_bf[idx] = f2bf(v);
    }
    for (size_t idx = idx0; idx < 2 * QT_SLICE; idx += stride) qT[idx] = 0;
    for (size_t idx = idx0; idx < (size_t)out_n; idx += stride) out[idx] = 12345.0f;
    if (idx0 < NBLK * FLAGSTRIDE) flags[idx0] = 0;
}

#define QLOAD(p) __hip_atomic_load((p), __ATOMIC_RELAXED, __HIP_MEMORY_SCOPE_AGENT)

// P2, fragment layout on BOTH operands: chunk c's A-fragment (adj, LDS) and
// B-fragments (q, LLC) for this lane live at base + c*512 ushorts. Every
// LDS/global access is a 64-lane x 16 B sequential burst — conflict-free.
// Loads are issued as one batch (R6-proven; R7's incremental loader spilled).
template<int NC>
__device__ __forceinline__ void p2_frag(const ushort_t* __restrict__ afrag,
                                        const ushort_t* __restrict__ q0,
                                        const ushort_t* __restrict__ q1,
                                        const int cbeg,
                                        floatx4& acc0, floatx4& acc1) {
    bf16x8 b0[NC], b1[NC];
#pragma unroll
    for (int i = 0; i < NC; i++) {
        b0[i] = *(const bf16x8*)(q0 + (size_t)(cbeg + i) * 512);
        b1[i] = *(const bf16x8*)(q1 + (size_t)(cbeg + i) * 512);
    }
#pragma unroll
    for (int i = 0; i < NC; i++) {
        bf16x8 av = *(const bf16x8*)(afrag + (size_t)(cbeg + i) * 512);
        acc0 = __builtin_amdgcn_mfma_f32_16x16x32_bf16(av, b0[i], acc0, 0, 0, 0);
        acc1 = __builtin_amdgcn_mfma_f32_16x16x32_bf16(av, b1[i], acc1, 0, 0, 0);
    }
}

// Persistent cooperative kernel, 512 threads (8 waves), block b owns nodes
// [16b,16b+16).
// R12 = R8 VERBATIM (proven best: 1640 us steady / 1735 dur).
// Protocol: flag-gated q exchange with producer drain (load-bearing — R4/R9
// proved undrained stores cause LLC line churn, R10 proved poll-first loses
// the gates-under-publish overlap, R11 proved the gate assignment is optimal).
//   * q_pack publish staging: P1b shfl-packs bf16 q pairs into a 1 KB
//     publish-ordered LDS buffer; wave0's publish = 1 ds_read_b128 + 2 stores
//   * pipelined dual-slot flag poll (2 loads in flight)
//   * fragment-ordered q slices + adj (coalesced publish, consume, LDS reads)
//   * dedicated wave0 (publish/flag/out-flush), waves 1-7 P2; c in registers;
//     out buffered 16 steps; x register prefetch; part[] ping-pong
template<bool RING>
__global__ void __launch_bounds__(NTHR, 2) rgcn_main(
    const float* __restrict__ x,      // [BSN][TT][DIN]
    const float* __restrict__ W_ih,   // [DIN][G4]
    const float* __restrict__ W_hh,   // [HS][G4]
    const float* __restrict__ bias,   // [G4]
    const float* __restrict__ W_q,    // [HS][HS]
    const float* __restrict__ b_q,    // [HS]
    const float* __restrict__ W_d,    // [HS]
    const float* __restrict__ b_d,    // [1]
    const ushort_t* __restrict__ adj_bf, // [MPAD][KPAD] bf16
    ushort_t* __restrict__ qT,        // ring: [TT] fragment slices; parity: [2][HS][KPAD]
    unsigned* __restrict__ flags,     // [NBLK] generation flags, FLAGSTRIDE apart
    float* __restrict__ out)          // [BSN][TT]
{
    const int tid  = threadIdx.x;
    const int blk  = blockIdx.x;
    const int base = blk * ROWS;
    const int wv   = tid >> 6;        // wave 0..7
    const int lane = tid & 63;

    __shared__ __align__(16) ushort_t adj_lds[NCHUNK * 512];  // 79 KB, fragment order
    __shared__ __align__(16) ushort_t q_pack[512];            // 1 KB publish staging (ring)
    __shared__ __align__(16) float x_lds[ROWS][DIN];
    __shared__ __align__(16) float h_lds[ROWS][HPAD];
    __shared__ __align__(16) float c_lds[ROWS][HPAD];         // parity path only
    __shared__ __align__(16) float q_lds[ROWS][HPAD];         // parity path only
    __shared__ __align__(16) float out_lds[ROWS][16];         // 16-step out buffer
    __shared__ float gates_lds[ROWS][G4];
    __shared__ float part[2][7][2][16][16];   // ping-pong, waves 1-7, 28 KB

    // ---- per-thread weights, pinned (opaque defs, no remat) ----
    const int u2 = tid & 63;
    float wih0[DIN], wih1[DIN], whh0[HS], whh1[HS];
#pragma unroll
    for (int k = 0; k < DIN; k++) {
        wih0[k] = W_ih[k*G4 + u2]; wih1[k] = W_ih[k*G4 + u2 + 64];
        asm volatile("" : "+v"(wih0[k]), "+v"(wih1[k]));
    }
#pragma unroll
    for (int k = 0; k < HS; k++) {
        whh0[k] = W_hh[k*G4 + u2]; whh1[k] = W_hh[k*G4 + u2 + 64];
        asm volatile("" : "+v"(whh0[k]), "+v"(whh1[k]));
    }
    const float bu0 = bias[u2], bu1 = bias[u2 + 64];

    // P1b/P3 mapping: thread = (node nq = tid>>5, hidden hq = tid&31) — wave-local
    const int hq = tid & 31;
    const int nq = tid >> 5;
    const float bqv = b_q[hq];
    const float wdv = W_d[hq];
    const float bdv = b_d[0];
    float c_reg = 0.0f;               // cell state in a register (ring path)

    // W_q column for this thread's hq, pinned in VGPRs (P1b register FMAs)
    float wqr[HS];
#pragma unroll
    for (int k = 0; k < HS; k++) {
        wqr[k] = W_q[k*HS + hq];
        asm volatile("" : "+v"(wqr[k]));
    }

    // q_pack dword slot for lanes<32 (nodes 2wv,2wv+1 at h=lane):
    //   d = (h>>4)*128 + ((h&15)|((wv>>2)<<4))*4 + (wv&3)
    const int qp_dw = (lane >> 4) * 128 + (((lane & 15) | ((wv >> 2) << 4)) << 2) + (wv & 3);

    // chunk split for waves 1-7: 12,12,12,11,11,11,10 (sum 79)
    int cbeg = 0, nch = 0;
    if (wv >= 1 && wv <= 3)      { cbeg = (wv - 1) * 12;      nch = 12; }
    else if (wv >= 4 && wv <= 6) { cbeg = 36 + (wv - 4) * 11; nch = 11; }
    else if (wv == 7)            { cbeg = 69;                 nch = 10; }
    // producers for this wave's chunks: [2*cbeg, 2*(cbeg+nch)) capped at NBLK
    const int pollbase = 2 * cbeg;
    const int pollcnt  = (wv == 0) ? 0
                       : ((2 * (cbeg + nch) < NBLK ? 2 * (cbeg + nch) : NBLK) - pollbase);
    const unsigned* pollf = flags + (size_t)(pollbase + (lane < pollcnt ? lane : 0)) * FLAGSTRIDE;
    const bool dopoll = (wv >= 1) && (lane < pollcnt);

    // x ownership (ring): wave w>=1 stages nodes 2w,2w+1; waves 1,2 also 0,1
    int xnode = -1, xk = lane & 15;
    if (wv >= 1 && lane < 32)                   xnode = 2*wv + (lane >> 4);
    else if ((wv == 1 || wv == 2) && lane < 48) xnode = wv - 1;
    const int xgn = base + xnode;
    const bool xok = (xnode >= 0) && (xgn < BSN);

    // ---- stage adj to LDS once, in MFMA-A-fragment order ----
    {
        const int n16_per_row = KPAD / 8;           // 316 uint4 per row
        for (int i = tid; i < ROWS * n16_per_row; i += NTHR) {
            int r = i / n16_per_row, o = i - r * n16_per_row;
            int c = o >> 2, kb = o & 3;
            *(uint4*)(adj_lds + (size_t)c * 512 + (size_t)(kb * 16 + r) * 8) =
                ((const uint4*)(adj_bf + (size_t)(base + r) * KPAD))[o];
        }
    }
    for (int i = tid; i < ROWS * HPAD; i += NTHR) {
        (&h_lds[0][0])[i] = 0.0f;
        (&c_lds[0][0])[i] = 0.0f;
    }
    __syncthreads();

    // gates helper: computes both gate halves for node nn (reads x_lds/h_lds)
    auto do_gates = [&](int nn) {
        float a0 = bu0, a1 = bu1;
#pragma unroll
        for (int k4 = 0; k4 < DIN/4; k4++) {
            float4 xv = *(const float4*)&x_lds[nn][k4*4];
            a0 = fmaf(xv.x, wih0[k4*4+0], a0); a1 = fmaf(xv.x, wih1[k4*4+0], a1);
            a0 = fmaf(xv.y, wih0[k4*4+1], a0); a1 = fmaf(xv.y, wih1[k4*4+1], a1);
            a0 = fmaf(xv.z, wih0[k4*4+2], a0); a1 = fmaf(xv.z, wih1[k4*4+2], a1);
            a0 = fmaf(xv.w, wih0[k4*4+3], a0); a1 = fmaf(xv.w, wih1[k4*4+3], a1);
        }
#pragma unroll
        for (int k4 = 0; k4 < HS/4; k4++) {
            float4 hv = *(const float4*)&h_lds[nn][k4*4];
            a0 = fmaf(hv.x, whh0[k4*4+0], a0); a1 = fmaf(hv.x, whh1[k4*4+0], a1);
            a0 = fmaf(hv.y, whh0[k4*4+1], a0); a1 = fmaf(hv.y, whh1[k4*4+1], a1);
            a0 = fmaf(hv.z, whh0[k4*4+2], a0); a1 = fmaf(hv.z, whh1[k4*4+2], a1);
            a0 = fmaf(hv.w, whh0[k4*4+3], a0); a1 = fmaf(hv.w, whh1[k4*4+3], a1);
        }
        gates_lds[nn][u2]      = sigmoid_fast(a0);
        gates_lds[nn][u2 + 64] = (u2 < HS) ? tanh_fast(a1) : sigmoid_fast(a1);
    };

    // P1b core: a = h_lds[nq][:] . wqr + b_q (register weights)
    auto p1b_acc = [&]() -> float {
        float a = bqv;
#pragma unroll
        for (int k4 = 0; k4 < HS/4; k4++) {
            float4 hv = *(const float4*)&h_lds[nq][k4*4];
            a = fmaf(hv.x, wqr[k4*4+0], a);
            a = fmaf(hv.y, wqr[k4*4+1], a);
            a = fmaf(hv.z, wqr[k4*4+2], a);
            a = fmaf(hv.w, wqr[k4*4+3], a);
        }
        return a;
    };

    if constexpr (RING) {
        // x prefetch for t = 0
        float xreg = xok ? x[(size_t)xgn * (TT*DIN) + xk] : 0.0f;

        // publish constants (wave0): block b -> chunk c=b>>1, half=b&1
        const int pc    = blk >> 1;
        const int phalf = blk & 1;
        const int preg  = lane >> 5;       // region 0/1
        const int pidx  = lane & 31;

        for (int t = 0; t < TT; t++) {
            const unsigned phase = (unsigned)(t + 1);
            const ushort_t* qslice = qT + (size_t)t * QT_SLICE;

            // ---- P1b: q_t = tanh(h_{t-1} @ W_q + b_q), shfl-packed bf16 ----
            {
                float qv = tanh_fast(p1b_acc());
                float qp = __shfl_xor(qv, 32);   // partner node's q (same h)
                if (lane < 32) {
                    unsigned val = (unsigned)f2bf(qv) | ((unsigned)f2bf(qp) << 16);
                    ((unsigned*)q_pack)[qp_dw] = val;
                }
            }
            __syncthreads();   // barrier A: q_pack complete; orders prior P3 writes

            if (wv == 0) {
                // ---- publish: one 16B LDS fragment read + 2x 8B agent stores ----
                union { bf16x8 v; u64_t u[2]; } fr;
                fr.v = *(const bf16x8*)(q_pack + preg * 256 + pidx * 8);
                u64_t* dst = (u64_t*)((ushort_t*)qslice + (size_t)preg * REGUS
                                      + (size_t)pc * 512 + phalf * 256 + pidx * 8);
                __hip_atomic_store(dst,     fr.u[0], __ATOMIC_RELAXED, __HIP_MEMORY_SCOPE_AGENT);
                __hip_atomic_store(dst + 1, fr.u[1], __ATOMIC_RELAXED, __HIP_MEMORY_SCOPE_AGENT);
                asm volatile("s_waitcnt vmcnt(0)" ::: "memory");
                if (lane == 0) {
                    __hip_atomic_store(flags + blk * FLAGSTRIDE, phase,
                                       __ATOMIC_RELAXED, __HIP_MEMORY_SCOPE_AGENT);
                }
                // ---- idle slot: flush previous 16-step out window ----
                if (t >= 16 && (t & 15) == 0) {
                    const int node = lane >> 2, qtr = lane & 3;
                    const int gn = base + node;
                    if (gn < BSN) {
                        *(float4*)(out + (size_t)gn * TT + (t - 16) + qtr * 4) =
                            *(const float4*)&out_lds[node][qtr * 4];
                    }
                }
            } else {
                // ---- shadow: x_lds write (prefetched) + next prefetch + gates ----
                if (xnode >= 0) {
                    x_lds[xnode][xk] = xok ? xreg : 0.0f;
                    const int tn = (t + 1 < TT) ? (t + 1) : (TT - 1);
                    if (xok) xreg = x[(size_t)xgn * (TT*DIN) + (size_t)tn * DIN + xk];
                }
                do_gates(2*wv);
                do_gates(2*wv + 1);
                if (wv <= 2) do_gates(wv - 1);   // cover wave 0's nodes
            }

            // ---- per-wave poll, dual-slot pipelined (2 loads in flight) ----
            if (dopoll) {
                unsigned a = QLOAD(pollf);
                unsigned b = QLOAD(pollf);
                while (a < phase) { a = b; b = QLOAD(pollf); }
            }

            // ---- P2 (waves 1-7): agg = adj(LDS frag) @ q(LLC frag) ----
            if (wv >= 1) {
                floatx4 acc0 = {0.f,0.f,0.f,0.f}, acc1 = {0.f,0.f,0.f,0.f};
                const int mcol = lane & 15;
                const int kb   = lane >> 4;
                const ushort_t* afrag = adj_lds + (size_t)lane * 8;
                const ushort_t* q0 = qslice + (size_t)lane * 8;
                const ushort_t* q1 = qslice + (size_t)REGUS + (size_t)lane * 8;
                if (wv <= 3)      p2_frag<12>(afrag, q0, q1, cbeg, acc0, acc1);
                else if (wv <= 6) p2_frag<11>(afrag, q0, q1, cbeg, acc0, acc1);
                else              p2_frag<10>(afrag, q0, q1, cbeg, acc0, acc1);
#pragma unroll
                for (int r = 0; r < 4; r++) {
                    part[t & 1][wv - 1][0][kb*4 + r][mcol] = acc0[r];
                    part[t & 1][wv - 1][1][kb*4 + r][mcol] = acc1[r];
                }
            }
            __syncthreads();   // RAW: part[] (P2 -> P3)

            // ---- P3: cell/hidden update + buffered out head ----
            {
                const int ntile = hq >> 4, col = hq & 15;
                float agg = 0.0f;
#pragma unroll
                for (int j = 0; j < 7; j++) agg += part[t & 1][j][ntile][nq][col];
                float iv = gates_lds[nq][hq];
                float fv = gates_lds[nq][HS + hq];
                float gv = gates_lds[nq][2*HS + hq];
                float ov = gates_lds[nq][3*HS + hq];
                float cv = fv * (c_reg + agg) + iv * gv;
                float hvv = ov * tanh_fast(cv);
                c_reg = cv;
                h_lds[nq][hq] = hvv;
                float p = hvv * wdv;
                p += __shfl_xor(p, 16);
                p += __shfl_xor(p, 8);
                p += __shfl_xor(p, 4);
                p += __shfl_xor(p, 2);
                p += __shfl_xor(p, 1);
                if (hq == 0) out_lds[nq][t & 15] = p + bdv;
            }
        }
        // ---- final out window [TT-16, TT) ----
        __syncthreads();
        if (wv == 0) {
            const int node = lane >> 2, qtr = lane & 3;
            const int gn = base + node;
            if (gn < BSN) {
                *(float4*)(out + (size_t)gn * TT + (TT - 16) + qtr * 4) =
                    *(const float4*)&out_lds[node][qtr * 4];
            }
        }
    } else {
        // ================= parity fallback: R2-proven flag structure =================
        for (int t = 0; t < TT; t++) {
            const unsigned phase = (unsigned)(t + 1);
            ushort_t* qbuf = qT + (size_t)(t & 1) * QT_SLICE;

            q_lds[nq][hq] = tanh_fast(p1b_acc());
            __syncthreads();

            if (tid < 256) {
                const int h0 = tid >> 3;
                const int pr = tid & 7;
                unsigned val = (unsigned)f2bf(q_lds[2*pr][h0])
                             | ((unsigned)f2bf(q_lds[2*pr + 1][h0]) << 16);
                unsigned* p = (unsigned*)(qbuf + (size_t)h0 * KPAD + base) + pr;
                __hip_atomic_store(p, val, __ATOMIC_RELAXED, __HIP_MEMORY_SCOPE_AGENT);
            }
            if (lane < 32) {
                const int node = 2*wv + (lane >> 4), k = lane & 15;
                const int gn = base + node;
                x_lds[node][k] = (gn < BSN) ? x[(size_t)gn * (TT*DIN) + (size_t)t*DIN + k] : 0.0f;
            }
            do_gates(2*wv);
            do_gates(2*wv + 1);
            asm volatile("s_waitcnt vmcnt(0)" ::: "memory");
            __syncthreads();
            if (tid == 0) {
                __hip_atomic_store(flags + blk * FLAGSTRIDE, phase,
                                   __ATOMIC_RELAXED, __HIP_MEMORY_SCOPE_AGENT);
            }
            if (tid < NBLK) {
                const unsigned* f = flags + tid * FLAGSTRIDE;
                while (QLOAD(f) < phase) {}
            }
            __syncthreads();

            {
                floatx4 acc0 = {0.f,0.f,0.f,0.f}, acc1 = {0.f,0.f,0.f,0.f};
                const int mcol = lane & 15;
                const int kb   = lane >> 4;
                const ushort_t* afrag = adj_lds + (size_t)lane * 8;   // fragment order
                const u64_t* q0 = (const u64_t*)(qbuf + (size_t)mcol        * KPAD) + kb*2;
                const u64_t* q1 = (const u64_t*)(qbuf + (size_t)(mcol + 16) * KPAD) + kb*2;
                const int cb2 = wv * 10;
                const int ce2 = (cb2 + 10 < NCHUNK) ? cb2 + 10 : NCHUNK;
                for (int c = cb2; c < ce2; c++) {
                    bf16x8 av = *(const bf16x8*)(afrag + (size_t)c * 512);
                    union { u64_t u[2]; bf16x8 v; } b0, b1;
                    b0.u[0] = QLOAD(q0 + c*8);
                    b0.u[1] = QLOAD(q0 + c*8 + 1);
                    b1.u[0] = QLOAD(q1 + c*8);
                    b1.u[1] = QLOAD(q1 + c*8 + 1);
                    acc0 = __builtin_amdgcn_mfma_f32_16x16x32_bf16(av, b0.v, acc0, 0, 0, 0);
                    acc1 = __builtin_amdgcn_mfma_f32_16x16x32_bf16(av, b1.v, acc1, 0, 0, 0);
                }
                // flat per-wave slots in part[] (8 waves x 512 floats)
                float* pw = &part[0][0][0][0][0] + (size_t)wv * 2 * 16 * 16;
#pragma unroll
                for (int r = 0; r < 4; r++) {
                    pw[(0*16 + kb*4 + r) * 16 + mcol] = acc0[r];
                    pw[(1*16 + kb*4 + r) * 16 + mcol] = acc1[r];
                }
            }
            __syncthreads();

            {
                const int ntile = hq >> 4, col = hq & 15;
                float agg = 0.0f;
                const float* pbase = &part[0][0][0][0][0];
#pragma unroll
                for (int w = 0; w < 8; w++) {
                    agg += pbase[(size_t)w * 2 * 16 * 16 + (ntile*16 + nq) * 16 + col];
                }
                float iv = gates_lds[nq][hq];
                float fv = gates_lds[nq][HS + hq];
                float gv = gates_lds[nq][2*HS + hq];
                float ov = gates_lds[nq][3*HS + hq];
                float cv = fv * (c_lds[nq][hq] + agg) + iv * gv;
                float hv = ov * tanh_fast(cv);
                c_lds[nq][hq] = cv;
                h_lds[nq][hq] = hv;
                float p = hv * wdv;
                p += __shfl_xor(p, 16);
                p += __shfl_xor(p, 8);
                p += __shfl_xor(p, 4);
                p += __shfl_xor(p, 2);
                p += __shfl_xor(p, 1);
                if (hq == 0) {
                    int gn = base + nq;
                    if (gn < BSN) out[(size_t)gn * TT + t] = p + bdv;
                }
            }
            __syncthreads();
        }
    }
}

extern "C" void kernel_launch(void* const* d_in, const int* in_sizes, int n_in,
                              void* d_out, int out_size, void* d_ws, size_t ws_size,
                              hipStream_t stream) {
    const float* x    = (const float*)d_in[0];
    const float* adj  = (const float*)d_in[1];
    const float* W_ih = (const float*)d_in[2];
    const float* W_hh = (const float*)d_in[3];
    const float* bias = (const float*)d_in[4];
    const float* W_q  = (const float*)d_in[5];
    const float* b_q  = (const float*)d_in[6];
    const float* W_d  = (const float*)d_in[7];
    const float* b_d  = (const float*)d_in[8];
    float* out = (float*)d_out;

    unsigned* flags = (unsigned*)((char*)d_ws + WS_FLAGS_OFF);
    ushort_t* adj_bf = (ushort_t*)((char*)d_ws + WS_ADJ_OFF);
    ushort_t* qT = (ushort_t*)((char*)d_ws + WS_QT_OFF);

    const bool ring = (ws_size >= WS_NEED_RING);   // constant across calls -> graph-safe

    // prep also pre-writes out=12345 (sentinel): if the cooperative launch is
    // rejected, absmax flags it.
    hipLaunchKernelGGL(prep, dim3(2048), dim3(256), 0, stream, adj, adj_bf, qT, flags,
                       out, out_size);

    const ushort_t* adj_bf_c = adj_bf;
    void* args[] = {
        (void*)&x, (void*)&W_ih, (void*)&W_hh, (void*)&bias, (void*)&W_q,
        (void*)&b_q, (void*)&W_d, (void*)&b_d, (void*)&adj_bf_c, (void*)&qT,
        (void*)&flags, (void*)&out
    };
    if (ring) {
        hipLaunchCooperativeKernel((void*)&rgcn_main<true>, dim3(NBLK), dim3(NTHR),
                                   args, 0, stream);
    } else {
        hipLaunchCooperativeKernel((void*)&rgcn_main<false>, dim3(NBLK), dim3(NTHR),
                                   args, 0, stream);
    }
}